// Round 5
// baseline (4852.092 us; speedup 1.0000x reference)
//
#include <hip/hip_runtime.h>
#include <cfloat>
#include <cstdint>

// Problem constants
constexpr int Bn   = 16;
constexpr int Nn   = 2048;
constexpr int Fin  = 8;
constexpr int Kn   = 35;
constexpr int NODES = Bn * Nn;          // 32768
constexpr int EDG   = NODES * Kn;       // 1146880
constexpr int NSTATB = 1024;            // stats grid blocks
constexpr float EPSV = 1e-5f;

// ---- monotone float<->u32 encoding for ordered compare / atomic max ----
__device__ __forceinline__ unsigned enc_f(float f){
    unsigned u = __float_as_uint(f);
    return (u & 0x80000000u) ? ~u : (u | 0x80000000u);
}
__device__ __forceinline__ float dec_f(unsigned e){
    unsigned u = (e & 0x80000000u) ? (e ^ 0x80000000u) : ~e;
    return __uint_as_float(u);
}

// ---- squared norms per node ----
template<int C>
__global__ __launch_bounds__(256) void sq_kernel(const float* __restrict__ h, float* __restrict__ sq){
    int i = blockIdx.x * 256 + threadIdx.x;
    if (i >= NODES) return;
    const float* p = h + (size_t)i * C;
    float s = 0.f;
#pragma unroll
    for (int c = 0; c < C; c++) s += p[c] * p[c];
    sq[i] = s;
}

// ---- kNN: 4 queries per block; block-wide dist phase, per-wave interpolation select ----
// Finds the set of Kn smallest (dist, index) keys (lexicographic tie-break) —
// identical set to top_k. Output order within the k slots is arbitrary
// (downstream only max-pools over k).
template<int C>
__global__ __launch_bounds__(256) void knn_kernel(const float* __restrict__ h, const float* __restrict__ sq,
                                                  int* __restrict__ idxout){
    __shared__ float dist[4][Nn];     // 32 KB
    __shared__ float hi4[4][C];
    __shared__ float sqi[4];
    int t  = threadIdx.x;
    int b  = blockIdx.x >> 9;               // Nn/4 = 512 blocks per batch
    int i0 = (blockIdx.x & 511) * 4;

    for (int i = t; i < 4 * C; i += 256)
        hi4[i / C][i % C] = h[((size_t)(b * Nn) + i0 + i / C) * C + (i % C)];
    if (t < 4) sqi[t] = sq[b * Nn + i0 + t];
    __syncthreads();

    for (int j = t; j < Nn; j += 256){
        const float4* hj = (const float4*)(h + ((size_t)(b * Nn) + j) * C);
        float d0 = 0.f, d1 = 0.f, d2 = 0.f, d3 = 0.f;
#pragma unroll
        for (int c4 = 0; c4 < C / 4; c4++){
            float4 v = hj[c4];
            d0 += hi4[0][4*c4] * v.x + hi4[0][4*c4+1] * v.y + hi4[0][4*c4+2] * v.z + hi4[0][4*c4+3] * v.w;
            d1 += hi4[1][4*c4] * v.x + hi4[1][4*c4+1] * v.y + hi4[1][4*c4+2] * v.z + hi4[1][4*c4+3] * v.w;
            d2 += hi4[2][4*c4] * v.x + hi4[2][4*c4+1] * v.y + hi4[2][4*c4+2] * v.z + hi4[2][4*c4+3] * v.w;
            d3 += hi4[3][4*c4] * v.x + hi4[3][4*c4+1] * v.y + hi4[3][4*c4+2] * v.z + hi4[3][4*c4+3] * v.w;
        }
        float sj = sq[b * Nn + j];
        dist[0][j] = sqi[0] + sj - 2.f * d0;
        dist[1][j] = sqi[1] + sj - 2.f * d1;
        dist[2][j] = sqi[2] + sj - 2.f * d2;
        dist[3][j] = sqi[3] + sj - 2.f * d3;
    }
    __syncthreads();

    // ---- per-wave select: wave w handles query i0+w; value j=s*64+lane in dv[s] ----
    int w = t >> 6, lane = t & 63;
    float dv[32];
#pragma unroll
    for (int s = 0; s < 32; s++) dv[s] = dist[w][s * 64 + lane];

    // wave min / max
    float lmin = dv[0], lmax = dv[0];
#pragma unroll
    for (int s = 1; s < 32; s++){ lmin = fminf(lmin, dv[s]); lmax = fmaxf(lmax, dv[s]); }
#pragma unroll
    for (int d = 1; d < 64; d <<= 1){
        lmin = fminf(lmin, __shfl_xor(lmin, d));
        lmax = fmaxf(lmax, __shfl_xor(lmax, d));
    }

    // interpolation search for threshold bracket:  invariant clo <= Kn < chi
    float lo = lmin;
    float hi = lmax + fmaxf(fabsf(lmax) * 1e-4f, 1e-6f);
    int clo = 0, chi = Nn;
    for (int it = 0; it < 12; it++){
        if (clo == Kn || chi - clo <= 4) break;
        float piv = lo + (hi - lo) * (((float)(Kn - clo) + 0.5f) / (float)(chi - clo));
        if (!(piv > lo && piv < hi)) piv = 0.5f * (lo + hi);
        if (!(piv > lo && piv < hi)) break;
        int c = 0;
#pragma unroll
        for (int s = 0; s < 32; s++) c += (dv[s] < piv) ? 1 : 0;
#pragma unroll
        for (int d = 1; d < 64; d <<= 1) c += __shfl_xor(c, d);
        if (c <= Kn){ lo = piv; clo = c; } else { hi = piv; chi = c; }
    }

    // masks: definite-select (dv < lo, exactly clo of them) and boundary band [lo, hi)
    unsigned below = 0u, band = 0u;
#pragma unroll
    for (int s = 0; s < 32; s++){
        float v = dv[s];
        below |= (v < lo)              ? (1u << s) : 0u;
        band  |= (v >= lo && v < hi)   ? (1u << s) : 0u;
    }

    // write definite selections at offsets [0, clo)
    size_t obase = ((size_t)(b * Nn) + i0 + w) * Kn;
    int myc = __popc(below);
    int inc = myc;
#pragma unroll
    for (int d = 1; d < 64; d <<= 1){
        int v = __shfl_up(inc, d);
        if (lane >= d) inc += v;
    }
    int o = inc - myc;
    unsigned bm0 = below;
    while (bm0){
        int s = __ffs(bm0) - 1; bm0 &= bm0 - 1;
        idxout[obase + (o++)] = s * 64 + lane;
    }

    // extract remaining r = Kn - clo from the band by (enc, index) wave-min
    int r = Kn - clo;
    unsigned bm = band;
    for (int e = 0; e < r; e++){
        unsigned long long best = ~0ull;
        unsigned tmp = bm;
        while (tmp){
            int s = __ffs(tmp) - 1; tmp &= tmp - 1;
            unsigned long long key = (((unsigned long long)enc_f(dv[s])) << 16) | (unsigned)(s * 64 + lane);
            best = (key < best) ? key : best;
        }
        unsigned long long wmin = best;
#pragma unroll
        for (int d = 1; d < 64; d <<= 1){
            unsigned long long ov = __shfl_xor(wmin, d);
            wmin = (ov < wmin) ? ov : wmin;
        }
        if (best == wmin && best != ~0ull){
            int j = (int)(wmin & 0xffffu);
            bm &= ~(1u << (j >> 6));
            idxout[obase + clo + e] = j;
        }
    }
}

// ---- pre1: p = x@(W1a-W1b)+b1, q = x@W1b  (layer-1 factorization) ----
__global__ __launch_bounds__(256) void pre1_kernel(const float* __restrict__ x,
        const float* __restrict__ w1, const float* __restrict__ b1,
        float* __restrict__ p, float* __restrict__ q){
    int t = threadIdx.x, w = t >> 6, c = t & 63;
    float wd[8], wb[8];
#pragma unroll
    for (int f = 0; f < 8; f++){
        float wbv = w1[(8 + f) * 64 + c];
        wb[f] = wbv;
        wd[f] = w1[f * 64 + c] - wbv;
    }
    float b1c = b1[c];
    int slot = blockIdx.x * 4 + w;                 // 2048 slots
    for (int it = 0; it < 16; it++){
        int node = slot + it * 2048;
        const float* xp = x + (size_t)node * Fin;
        float pv = b1c, qv = 0.f;
#pragma unroll
        for (int f = 0; f < 8; f++){
            float xv = xp[f];
            pv += xv * wd[f]; qv += xv * wb[f];
        }
        p[(size_t)node * 64 + c] = pv;
        q[(size_t)node * 64 + c] = qv;
    }
}

// ---- stats pass 1: moments of z1 = p[i]+q[j] over edges ----
__global__ __launch_bounds__(256) void stats1_kernel(const float* __restrict__ p, const float* __restrict__ q,
        const int* __restrict__ idx, float* __restrict__ sumP, float* __restrict__ ssqP){
    __shared__ float red[2][4][64];
    int t = threadIdx.x, w = t >> 6, c = t & 63;
    float s = 0.f, ss = 0.f;
    int slot = blockIdx.x * 4 + w;                 // 4096 slots
    for (int it = 0; it < 8; it++){
        int node = slot + it * 4096;
        int b = node >> 11;
        float pc = p[(size_t)node * 64 + c];
        const int* ip = idx + (size_t)node * Kn;
        for (int k = 0; k < Kn; k++){
            int j = ip[k];
            float z = pc + q[((size_t)(b << 11) + j) * 64 + c];
            s += z; ss += z * z;
        }
    }
    red[0][w][c] = s; red[1][w][c] = ss;
    __syncthreads();
    if (w == 0){
        sumP[blockIdx.x * 64 + c] = red[0][0][c] + red[0][1][c] + red[0][2][c] + red[0][3][c];
        ssqP[blockIdx.x * 64 + c] = red[1][0][c] + red[1][1][c] + red[1][2][c] + red[1][3][c];
    }
}

// ---- finalize BN params from partials ----
__global__ void finalize_kernel(const float* __restrict__ sumP, const float* __restrict__ ssqP,
        const float* __restrict__ gg, const float* __restrict__ bt,
        float* __restrict__ scale, float* __restrict__ shift, float inv_count){
    int c = threadIdx.x;   // 64 threads
    float s = 0.f, q = 0.f;
    for (int i = 0; i < NSTATB; i++){ s += sumP[i * 64 + c]; q += ssqP[i * 64 + c]; }
    float mu  = s * inv_count;
    float var = q * inv_count - mu * mu;
    float sc  = gg[c] / sqrtf(var + EPSV);
    scale[c] = sc;
    shift[c] = bt[c] - mu * sc;
}

// ---- stats pass 2: z1 -> bn1+relu -> z2 (64x64 matvec, weights in regs), moments ----
__global__ __launch_bounds__(256) void stats2_kernel(const float* __restrict__ p, const float* __restrict__ q,
        const int* __restrict__ idx,
        const float* __restrict__ sc1v, const float* __restrict__ sh1v,
        const float* __restrict__ w2, const float* __restrict__ b2,
        float* __restrict__ sumP, float* __restrict__ ssqP){
    __shared__ float hsh[4][2][64];
    __shared__ float red[2][4][64];
    int t = threadIdx.x, w = t >> 6, c = t & 63;
    float w2c[64];
#pragma unroll
    for (int f = 0; f < 64; f++) w2c[f] = w2[f * 64 + c];
    float sc1 = sc1v[c], sh1 = sh1v[c], b2c = b2[c];
    float s = 0.f, ss = 0.f;
    int slot = blockIdx.x * 4 + w;
    for (int it = 0; it < 8; it++){
        int node = slot + it * 4096;
        int b = node >> 11;
        float pc = p[(size_t)node * 64 + c];
        const int* ip = idx + (size_t)node * Kn;
        for (int k = 0; k < Kn; k++){
            int j = ip[k];
            float z = pc + q[((size_t)(b << 11) + j) * 64 + c];
            float h1 = fmaxf(0.f, z * sc1 + sh1);
            hsh[w][k & 1][c] = h1;
            const float4* h4 = (const float4*)hsh[w][k & 1];
            float z2 = b2c;
#pragma unroll
            for (int f4 = 0; f4 < 16; f4++){
                float4 hv = h4[f4];
                z2 += hv.x * w2c[4*f4] + hv.y * w2c[4*f4+1] + hv.z * w2c[4*f4+2] + hv.w * w2c[4*f4+3];
            }
            s += z2; ss += z2 * z2;
        }
    }
    red[0][w][c] = s; red[1][w][c] = ss;
    __syncthreads();
    if (w == 0){
        sumP[blockIdx.x * 64 + c] = red[0][0][c] + red[0][1][c] + red[0][2][c] + red[0][3][c];
        ssqP[blockIdx.x * 64 + c] = red[1][0][c] + red[1][1][c] + red[1][2][c] + red[1][3][c];
    }
}

// ---- conv1: wave-per-node, layers 2/3 as register-weight matvecs, max over k ----
__global__ __launch_bounds__(256) void conv1_kernel(const float* __restrict__ p, const float* __restrict__ q,
        const int* __restrict__ idx,
        const float* __restrict__ sc1v, const float* __restrict__ sh1v,
        const float* __restrict__ w2, const float* __restrict__ b2,
        const float* __restrict__ sc2v, const float* __restrict__ sh2v,
        const float* __restrict__ w3, const float* __restrict__ b3,
        float* __restrict__ x1){
    __shared__ float hA[4][2][64];
    __shared__ float hB[4][2][64];
    int t = threadIdx.x, w = t >> 6, c = t & 63;
    float w2c[64], w3c[64];
#pragma unroll
    for (int f = 0; f < 64; f++){ w2c[f] = w2[f * 64 + c]; w3c[f] = w3[f * 64 + c]; }
    float sc1 = sc1v[c], sh1 = sh1v[c], sc2 = sc2v[c], sh2 = sh2v[c];
    float b2c = b2[c], b3c = b3[c];
    int node = blockIdx.x * 4 + w;
    int b = node >> 11;
    float pc = p[(size_t)node * 64 + c];
    const int* ip = idx + (size_t)node * Kn;
    float acc = -FLT_MAX;
    for (int k = 0; k < Kn; k++){
        int j = ip[k];
        float z = pc + q[((size_t)(b << 11) + j) * 64 + c];
        float h1 = fmaxf(0.f, z * sc1 + sh1);
        hA[w][k & 1][c] = h1;
        const float4* h4 = (const float4*)hA[w][k & 1];
        float z2 = b2c;
#pragma unroll
        for (int f4 = 0; f4 < 16; f4++){
            float4 hv = h4[f4];
            z2 += hv.x * w2c[4*f4] + hv.y * w2c[4*f4+1] + hv.z * w2c[4*f4+2] + hv.w * w2c[4*f4+3];
        }
        float h2 = fmaxf(0.f, z2 * sc2 + sh2);
        hB[w][k & 1][c] = h2;
        const float4* g4 = (const float4*)hB[w][k & 1];
        float z3 = b3c;
#pragma unroll
        for (int f4 = 0; f4 < 16; f4++){
            float4 hv = g4[f4];
            z3 += hv.x * w3c[4*f4] + hv.y * w3c[4*f4+1] + hv.z * w3c[4*f4+2] + hv.w * w3c[4*f4+3];
        }
        acc = fmaxf(acc, z3);
    }
    x1[(size_t)node * 64 + c] = acc;
}

// ---- pre2: u = x1@(W4a-W4b)+b4 (into x2 buffer), v = x1@W4b ----
__global__ __launch_bounds__(256) void pre2_kernel(const float* __restrict__ x1,
        const float* __restrict__ w4, const float* __restrict__ b4,
        float* __restrict__ u, float* __restrict__ v){
    __shared__ float x1s[16][64];
    int t = threadIdx.x;
    int c = t & 127, h = t >> 7;
    float wd[64], wb[64];
#pragma unroll
    for (int f = 0; f < 64; f++){
        float wbv = w4[(64 + f) * 128 + c];
        wb[f] = wbv;
        wd[f] = w4[f * 128 + c] - wbv;
    }
    float b4c = b4[c];
    int base = blockIdx.x * 16;
    for (int i = t; i < 16 * 64; i += 256)
        x1s[i >> 6][i & 63] = x1[(size_t)(base + (i >> 6)) * 64 + (i & 63)];
    __syncthreads();
    for (int n = 0; n < 8; n++){
        int node = base + h * 8 + n;
        const float4* xr = (const float4*)x1s[h * 8 + n];
        float uv = b4c, vv = 0.f;
#pragma unroll
        for (int f4 = 0; f4 < 16; f4++){
            float4 xv = xr[f4];
            uv += xv.x * wd[4*f4] + xv.y * wd[4*f4+1] + xv.z * wd[4*f4+2] + xv.w * wd[4*f4+3];
            vv += xv.x * wb[4*f4] + xv.y * wb[4*f4+1] + xv.z * wb[4*f4+2] + xv.w * wb[4*f4+3];
        }
        u[(size_t)node * 128 + c] = uv;
        v[(size_t)node * 128 + c] = vv;
    }
}

// ---- gmax2: x2[i][c] = u[i][c] + max_k v[j_k][c]  (x2 holds u on entry) ----
__global__ __launch_bounds__(256) void gmax2_kernel(const float* __restrict__ v, const int* __restrict__ idx,
        float* __restrict__ x2){
    int t = threadIdx.x, g = t >> 7, c = t & 127;
    int node = blockIdx.x * 2 + g;
    int b = node >> 11;
    const int* ip = idx + (size_t)node * Kn;
    float vm = -FLT_MAX;
    for (int k = 0; k < Kn; k++){
        int j = ip[k];
        vm = fmaxf(vm, v[((size_t)(b << 11) + j) * 128 + c]);
    }
    x2[(size_t)node * 128 + c] += vm;
}

// ---- out = cat(x1,x2) @ w5 + b5, global max over nodes (encoded atomics) ----
__global__ __launch_bounds__(256) void outpool_kernel(const float* __restrict__ x1, const float* __restrict__ x2,
        const float* __restrict__ w5, const float* __restrict__ b5, unsigned* __restrict__ pooled){
    __shared__ float rows[8][192];
    int t = threadIdx.x;
    int node0 = blockIdx.x * 8;
    for (int i = t; i < 8 * 192; i += 256){
        int e = i / 192, f = i - e * 192;
        int nd = node0 + e;
        rows[e][f] = (f < 64) ? x1[(size_t)nd * 64 + f] : x2[(size_t)nd * 128 + f - 64];
    }
    __syncthreads();
    float z[8];
#pragma unroll
    for (int e = 0; e < 8; e++) z[e] = b5[t];
    for (int f = 0; f < 192; f++){
        float w = w5[f * 256 + t];
#pragma unroll
        for (int e = 0; e < 8; e++) z[e] += rows[e][f] * w;
    }
    float m = z[0];
#pragma unroll
    for (int e = 1; e < 8; e++) m = fmaxf(m, z[e]);
    int b = node0 >> 11;
    atomicMax(&pooled[b * 256 + t], enc_f(m));
}

// ---- head: decode pooled, MLP [256,128,64,4] with training-mode BN over 16 ----
__global__ __launch_bounds__(256) void head_kernel(const unsigned* __restrict__ pooledE,
        const float* __restrict__ w6, const float* __restrict__ b6, const float* __restrict__ g6, const float* __restrict__ bt6,
        const float* __restrict__ w7, const float* __restrict__ b7, const float* __restrict__ g7, const float* __restrict__ bt7,
        const float* __restrict__ w8, const float* __restrict__ b8, float* __restrict__ out){
    __shared__ float P[16][256];
    __shared__ float H6[16][128];
    __shared__ float H7[16][64];
    int t = threadIdx.x;
    for (int i = t; i < 16 * 256; i += 256) P[i >> 8][i & 255] = dec_f(pooledE[i]);
    __syncthreads();
    for (int i = t; i < 16 * 128; i += 256){
        int r = i >> 7, c = i & 127;
        float z = b6[c];
        for (int f = 0; f < 256; f++) z += P[r][f] * w6[f * 128 + c];
        H6[r][c] = z;
    }
    __syncthreads();
    if (t < 128){
        float s = 0.f, q = 0.f;
        for (int r = 0; r < 16; r++){ float v = H6[r][t]; s += v; q += v * v; }
        float mu = s * (1.f / 16.f);
        float var = q * (1.f / 16.f) - mu * mu;
        float sc = g6[t] / sqrtf(var + EPSV);
        float sh = bt6[t] - mu * sc;
        for (int r = 0; r < 16; r++) H6[r][t] = fmaxf(0.f, H6[r][t] * sc + sh);
    }
    __syncthreads();
    for (int i = t; i < 16 * 64; i += 256){
        int r = i >> 6, c = i & 63;
        float z = b7[c];
        for (int f = 0; f < 128; f++) z += H6[r][f] * w7[f * 64 + c];
        H7[r][c] = z;
    }
    __syncthreads();
    if (t < 64){
        float s = 0.f, q = 0.f;
        for (int r = 0; r < 16; r++){ float v = H7[r][t]; s += v; q += v * v; }
        float mu = s * (1.f / 16.f);
        float var = q * (1.f / 16.f) - mu * mu;
        float sc = g7[t] / sqrtf(var + EPSV);
        float sh = bt7[t] - mu * sc;
        for (int r = 0; r < 16; r++) H7[r][t] = fmaxf(0.f, H7[r][t] * sc + sh);
    }
    __syncthreads();
    if (t < 64){
        int r = t >> 2, c = t & 3;
        float z = b8[c];
        for (int f = 0; f < 64; f++) z += H7[r][f] * w8[f * 4 + c];
        out[t] = z;
    }
}

extern "C" void kernel_launch(void* const* d_in, const int* in_sizes, int n_in,
                              void* d_out, int out_size, void* d_ws, size_t ws_size,
                              hipStream_t stream){
    const float* x   = (const float*)d_in[0];
    const float* w1  = (const float*)d_in[1];
    const float* b1  = (const float*)d_in[2];
    const float* g1  = (const float*)d_in[3];
    const float* bt1 = (const float*)d_in[4];
    const float* w2  = (const float*)d_in[5];
    const float* b2  = (const float*)d_in[6];
    const float* g2  = (const float*)d_in[7];
    const float* bt2 = (const float*)d_in[8];
    const float* w3  = (const float*)d_in[9];
    const float* b3  = (const float*)d_in[10];
    const float* w4  = (const float*)d_in[11];
    const float* b4  = (const float*)d_in[12];
    const float* w5  = (const float*)d_in[13];
    const float* b5  = (const float*)d_in[14];
    const float* w6  = (const float*)d_in[15];
    const float* b6  = (const float*)d_in[16];
    const float* g6  = (const float*)d_in[17];
    const float* bt6 = (const float*)d_in[18];
    const float* w7  = (const float*)d_in[19];
    const float* b7  = (const float*)d_in[20];
    const float* g7  = (const float*)d_in[21];
    const float* bt7 = (const float*)d_in[22];
    const float* w8  = (const float*)d_in[23];
    const float* b8  = (const float*)d_in[24];
    float* out = (float*)d_out;

    char* ws = (char*)d_ws;
    size_t off = 0;
    auto alloc = [&](size_t bytes)->char*{
        char* p = ws + off;
        off += (bytes + 255) & ~(size_t)255;
        return p;
    };
    int*      idx1   = (int*)alloc((size_t)EDG * 4);
    int*      idx2   = (int*)alloc((size_t)EDG * 4);
    float*    sq1    = (float*)alloc((size_t)NODES * 4);
    float*    sq2    = (float*)alloc((size_t)NODES * 4);
    float*    x1     = (float*)alloc((size_t)NODES * 64 * 4);
    float*    x2     = (float*)alloc((size_t)NODES * 128 * 4);
    float*    sumP   = (float*)alloc((size_t)NSTATB * 64 * 4);
    float*    ssqP   = (float*)alloc((size_t)NSTATB * 64 * 4);
    float*    scale1 = (float*)alloc(64 * 4);
    float*    shift1 = (float*)alloc(64 * 4);
    float*    scale2 = (float*)alloc(64 * 4);
    float*    shift2 = (float*)alloc(64 * 4);
    unsigned* pooled = (unsigned*)alloc((size_t)Bn * 256 * 4);
    float*    p      = (float*)alloc((size_t)NODES * 64 * 4);
    float*    q      = (float*)alloc((size_t)NODES * 64 * 4);
    float*    v      = p;   // overlay: p,q are dead once conv1 finishes; v = 128 floats/node spans p+q

    hipMemsetAsync(pooled, 0, (size_t)Bn * 256 * 4, stream);

    sq_kernel<8><<<(NODES + 255) / 256, 256, 0, stream>>>(x, sq1);
    knn_kernel<8><<<NODES / 4, 256, 0, stream>>>(x, sq1, idx1);
    pre1_kernel<<<512, 256, 0, stream>>>(x, w1, b1, p, q);
    stats1_kernel<<<NSTATB, 256, 0, stream>>>(p, q, idx1, sumP, ssqP);
    finalize_kernel<<<1, 64, 0, stream>>>(sumP, ssqP, g1, bt1, scale1, shift1, 1.0f / (float)EDG);
    stats2_kernel<<<NSTATB, 256, 0, stream>>>(p, q, idx1, scale1, shift1, w2, b2, sumP, ssqP);
    finalize_kernel<<<1, 64, 0, stream>>>(sumP, ssqP, g2, bt2, scale2, shift2, 1.0f / (float)EDG);
    conv1_kernel<<<NODES / 4, 256, 0, stream>>>(p, q, idx1, scale1, shift1,
                                                w2, b2, scale2, shift2, w3, b3, x1);
    sq_kernel<64><<<(NODES + 255) / 256, 256, 0, stream>>>(x1, sq2);
    knn_kernel<64><<<NODES / 4, 256, 0, stream>>>(x1, sq2, idx2);
    pre2_kernel<<<NODES / 16, 256, 0, stream>>>(x1, w4, b4, x2, v);
    gmax2_kernel<<<NODES / 2, 256, 0, stream>>>(v, idx2, x2);
    outpool_kernel<<<NODES / 8, 256, 0, stream>>>(x1, x2, w5, b5, pooled);
    head_kernel<<<1, 256, 0, stream>>>(pooled, w6, b6, g6, bt6, w7, b7, g7, bt7, w8, b8, out);
}

// Round 6
// 2199.270 us; speedup vs baseline: 2.2062x; 2.2062x over previous
//
#include <hip/hip_runtime.h>
#include <cfloat>
#include <cstdint>

// Problem constants
constexpr int Bn   = 16;
constexpr int Nn   = 2048;
constexpr int Fin  = 8;
constexpr int Kn   = 35;
constexpr int NODES = Bn * Nn;          // 32768
constexpr int EDG   = NODES * Kn;       // 1146880
constexpr int NSTATB = 1024;            // stats grid blocks
constexpr float EPSV = 1e-5f;

// ---- monotone float<->u32 encoding for ordered compare / atomic max ----
__device__ __forceinline__ unsigned enc_f(float f){
    unsigned u = __float_as_uint(f);
    return (u & 0x80000000u) ? ~u : (u | 0x80000000u);
}
__device__ __forceinline__ float dec_f(unsigned e){
    unsigned u = (e & 0x80000000u) ? (e ^ 0x80000000u) : ~e;
    return __uint_as_float(u);
}

// ---- squared norms per node ----
template<int C>
__global__ __launch_bounds__(256) void sq_kernel(const float* __restrict__ h, float* __restrict__ sq){
    int i = blockIdx.x * 256 + threadIdx.x;
    if (i >= NODES) return;
    const float* p = h + (size_t)i * C;
    float s = 0.f;
#pragma unroll
    for (int c = 0; c < C; c++) s += p[c] * p[c];
    sq[i] = s;
}

// ---- kNN: 4 queries per block; block-wide dist phase, per-wave threshold search.
// All wave reductions are ballot+popc (no bpermute chains). Finds the exact set of
// Kn smallest (dist, index) keys (lexicographic tie-break) == top_k set.
template<int C>
__global__ __launch_bounds__(256) void knn_kernel(const float* __restrict__ h, const float* __restrict__ sq,
                                                  int* __restrict__ idxout){
    __shared__ float dist[4][Nn];                 // 32 KB
    __shared__ float hi4[4][C];
    __shared__ float sqi[4];
    __shared__ unsigned long long keybuf[4][64];  // 2 KB: boundary-band keys
    int t  = threadIdx.x;
    int b  = blockIdx.x >> 9;               // Nn/4 = 512 blocks per batch
    int i0 = (blockIdx.x & 511) * 4;

    for (int i = t; i < 4 * C; i += 256)
        hi4[i / C][i % C] = h[((size_t)(b * Nn) + i0 + i / C) * C + (i % C)];
    if (t < 4) sqi[t] = sq[b * Nn + i0 + t];
    __syncthreads();

    for (int j = t; j < Nn; j += 256){
        const float4* hj = (const float4*)(h + ((size_t)(b * Nn) + j) * C);
        float d0 = 0.f, d1 = 0.f, d2 = 0.f, d3 = 0.f;
#pragma unroll
        for (int c4 = 0; c4 < C / 4; c4++){
            float4 v = hj[c4];
            d0 += hi4[0][4*c4] * v.x + hi4[0][4*c4+1] * v.y + hi4[0][4*c4+2] * v.z + hi4[0][4*c4+3] * v.w;
            d1 += hi4[1][4*c4] * v.x + hi4[1][4*c4+1] * v.y + hi4[1][4*c4+2] * v.z + hi4[1][4*c4+3] * v.w;
            d2 += hi4[2][4*c4] * v.x + hi4[2][4*c4+1] * v.y + hi4[2][4*c4+2] * v.z + hi4[2][4*c4+3] * v.w;
            d3 += hi4[3][4*c4] * v.x + hi4[3][4*c4+1] * v.y + hi4[3][4*c4+2] * v.z + hi4[3][4*c4+3] * v.w;
        }
        float sj = sq[b * Nn + j];
        dist[0][j] = sqi[0] + sj - 2.f * d0;
        dist[1][j] = sqi[1] + sj - 2.f * d1;
        dist[2][j] = sqi[2] + sj - 2.f * d2;
        dist[3][j] = sqi[3] + sj - 2.f * d3;
    }
    __syncthreads();

    // ---- per-wave select: wave w handles query i0+w; value j=s*64+lane in dv[s] ----
    int w = t >> 6, lane = t & 63;
    float dv[32];
#pragma unroll
    for (int s = 0; s < 32; s++) dv[s] = dist[w][s * 64 + lane];

    // one-time wave min/max (only shuffle chain in the kernel)
    float lmin = dv[0], lmax = dv[0];
#pragma unroll
    for (int s = 1; s < 32; s++){ lmin = fminf(lmin, dv[s]); lmax = fmaxf(lmax, dv[s]); }
#pragma unroll
    for (int d = 1; d < 64; d <<= 1){
        lmin = fminf(lmin, __shfl_xor(lmin, d));
        lmax = fmaxf(lmax, __shfl_xor(lmax, d));
    }

    // hybrid interpolation/bisection on values; counts via ballot+popc.
    // invariant: count(<lo)=clo <= Kn < chi=count(<hi)
    float lo = lmin;
    float hi = lmax + fmaxf(fabsf(lmax) * 1e-5f, 1e-6f);
    int clo = 0, chi = Nn;
    for (int it = 0; it < 24; it++){
        if (clo == Kn || chi - clo <= 8) break;
        float piv;
        if (it & 1) piv = 0.5f * (lo + hi);
        else        piv = lo + (hi - lo) * (((float)(Kn - clo) + 0.5f) / (float)(chi - clo));
        if (!(piv > lo && piv < hi)) piv = 0.5f * (lo + hi);
        if (!(piv > lo && piv < hi)) break;   // ulp-stalled (ties): band handles it
        int c = 0;
#pragma unroll
        for (int s = 0; s < 32; s++) c += __popcll(__ballot(dv[s] < piv));
        if (c <= Kn){ lo = piv; clo = c; } else { hi = piv; chi = c; }
    }

    unsigned below = 0u, band = 0u;
#pragma unroll
    for (int s = 0; s < 32; s++){
        float v = dv[s];
        below |= (v < lo)            ? (1u << s) : 0u;
        band  |= (v >= lo && v < hi) ? (1u << s) : 0u;
    }
    int r  = Kn - clo;        // picks needed from band
    int bc = chi - clo;       // band population (wave-wide, exact)

    size_t obase = ((size_t)(b * Nn) + i0 + w) * Kn;
    unsigned long long me_lower = (1ull << lane) - 1ull;

    // write definite selections [0, clo) via ballot compaction (order: by slot, then lane)
    int off = 0;
#pragma unroll
    for (int s = 0; s < 32; s++){
        unsigned long long m = __ballot((below >> s) & 1);
        if ((below >> s) & 1){
            int o = off + __popcll(m & me_lower);
            idxout[obase + o] = s * 64 + lane;
        }
        off += __popcll(m);
    }

    if (r > 0){
        if (bc <= 64){
            // compact band keys into LDS via ballots
            int boff = 0;
#pragma unroll
            for (int s = 0; s < 32; s++){
                unsigned long long m = __ballot((band >> s) & 1);
                if ((band >> s) & 1){
                    int o = boff + __popcll(m & me_lower);
                    keybuf[w][o] = (((unsigned long long)enc_f(dv[s])) << 16) | (unsigned)(s * 64 + lane);
                }
                boff += __popcll(m);
            }
            // lane c ranks key c against all bc keys (broadcast LDS reads, no reductions)
            if (lane < bc){
                unsigned long long myk = keybuf[w][lane];
                int rank = 0;
                for (int j2 = 0; j2 < bc; j2++) rank += (keybuf[w][j2] < myk) ? 1 : 0;
                if (rank < r) idxout[obase + clo + rank] = (int)(myk & 0xffffu);
            }
        } else {
            // rare fallback (heavy ties / stalled search): iterative wave-min extraction
            unsigned bm = band;
            for (int e = 0; e < r; e++){
                unsigned long long best = ~0ull;
                unsigned tmp = bm;
                while (tmp){
                    int s = __ffs(tmp) - 1; tmp &= tmp - 1;
                    unsigned long long key = (((unsigned long long)enc_f(dv[s])) << 16) | (unsigned)(s * 64 + lane);
                    best = (key < best) ? key : best;
                }
                unsigned long long wmin = best;
#pragma unroll
                for (int d = 1; d < 64; d <<= 1){
                    unsigned long long ov = __shfl_xor(wmin, d);
                    wmin = (ov < wmin) ? ov : wmin;
                }
                if (best == wmin && best != ~0ull){
                    int j2 = (int)(wmin & 0xffffu);
                    bm &= ~(1u << (j2 >> 6));
                    idxout[obase + clo + e] = j2;
                }
            }
        }
    }
}

// ---- pre1: p = x@(W1a-W1b)+b1, q = x@W1b  (layer-1 factorization) ----
__global__ __launch_bounds__(256) void pre1_kernel(const float* __restrict__ x,
        const float* __restrict__ w1, const float* __restrict__ b1,
        float* __restrict__ p, float* __restrict__ q){
    int t = threadIdx.x, w = t >> 6, c = t & 63;
    float wd[8], wb[8];
#pragma unroll
    for (int f = 0; f < 8; f++){
        float wbv = w1[(8 + f) * 64 + c];
        wb[f] = wbv;
        wd[f] = w1[f * 64 + c] - wbv;
    }
    float b1c = b1[c];
    int slot = blockIdx.x * 4 + w;                 // 2048 slots
    for (int it = 0; it < 16; it++){
        int node = slot + it * 2048;
        const float* xp = x + (size_t)node * Fin;
        float pv = b1c, qv = 0.f;
#pragma unroll
        for (int f = 0; f < 8; f++){
            float xv = xp[f];
            pv += xv * wd[f]; qv += xv * wb[f];
        }
        p[(size_t)node * 64 + c] = pv;
        q[(size_t)node * 64 + c] = qv;
    }
}

// ---- stats pass 1: moments of z1 = p[i]+q[j] over edges ----
__global__ __launch_bounds__(256) void stats1_kernel(const float* __restrict__ p, const float* __restrict__ q,
        const int* __restrict__ idx, float* __restrict__ sumP, float* __restrict__ ssqP){
    __shared__ float red[2][4][64];
    int t = threadIdx.x, w = t >> 6, c = t & 63;
    float s = 0.f, ss = 0.f;
    int slot = blockIdx.x * 4 + w;                 // 4096 slots
    for (int it = 0; it < 8; it++){
        int node = slot + it * 4096;
        int b = node >> 11;
        float pc = p[(size_t)node * 64 + c];
        const int* ip = idx + (size_t)node * Kn;
        for (int k = 0; k < Kn; k++){
            int j = ip[k];
            float z = pc + q[((size_t)(b << 11) + j) * 64 + c];
            s += z; ss += z * z;
        }
    }
    red[0][w][c] = s; red[1][w][c] = ss;
    __syncthreads();
    if (w == 0){
        sumP[blockIdx.x * 64 + c] = red[0][0][c] + red[0][1][c] + red[0][2][c] + red[0][3][c];
        ssqP[blockIdx.x * 64 + c] = red[1][0][c] + red[1][1][c] + red[1][2][c] + red[1][3][c];
    }
}

// ---- finalize BN params from partials ----
__global__ void finalize_kernel(const float* __restrict__ sumP, const float* __restrict__ ssqP,
        const float* __restrict__ gg, const float* __restrict__ bt,
        float* __restrict__ scale, float* __restrict__ shift, float inv_count){
    int c = threadIdx.x;   // 64 threads
    float s = 0.f, q = 0.f;
    for (int i = 0; i < NSTATB; i++){ s += sumP[i * 64 + c]; q += ssqP[i * 64 + c]; }
    float mu  = s * inv_count;
    float var = q * inv_count - mu * mu;
    float sc  = gg[c] / sqrtf(var + EPSV);
    scale[c] = sc;
    shift[c] = bt[c] - mu * sc;
}

// ---- stats pass 2: z1 -> bn1+relu -> z2 (64x64 matvec, weights in regs), moments ----
__global__ __launch_bounds__(256) void stats2_kernel(const float* __restrict__ p, const float* __restrict__ q,
        const int* __restrict__ idx,
        const float* __restrict__ sc1v, const float* __restrict__ sh1v,
        const float* __restrict__ w2, const float* __restrict__ b2,
        float* __restrict__ sumP, float* __restrict__ ssqP){
    __shared__ float hsh[4][2][64];
    __shared__ float red[2][4][64];
    int t = threadIdx.x, w = t >> 6, c = t & 63;
    float w2c[64];
#pragma unroll
    for (int f = 0; f < 64; f++) w2c[f] = w2[f * 64 + c];
    float sc1 = sc1v[c], sh1 = sh1v[c], b2c = b2[c];
    float s = 0.f, ss = 0.f;
    int slot = blockIdx.x * 4 + w;
    for (int it = 0; it < 8; it++){
        int node = slot + it * 4096;
        int b = node >> 11;
        float pc = p[(size_t)node * 64 + c];
        const int* ip = idx + (size_t)node * Kn;
        for (int k = 0; k < Kn; k++){
            int j = ip[k];
            float z = pc + q[((size_t)(b << 11) + j) * 64 + c];
            float h1 = fmaxf(0.f, z * sc1 + sh1);
            hsh[w][k & 1][c] = h1;
            const float4* h4 = (const float4*)hsh[w][k & 1];
            float z2 = b2c;
#pragma unroll
            for (int f4 = 0; f4 < 16; f4++){
                float4 hv = h4[f4];
                z2 += hv.x * w2c[4*f4] + hv.y * w2c[4*f4+1] + hv.z * w2c[4*f4+2] + hv.w * w2c[4*f4+3];
            }
            s += z2; ss += z2 * z2;
        }
    }
    red[0][w][c] = s; red[1][w][c] = ss;
    __syncthreads();
    if (w == 0){
        sumP[blockIdx.x * 64 + c] = red[0][0][c] + red[0][1][c] + red[0][2][c] + red[0][3][c];
        ssqP[blockIdx.x * 64 + c] = red[1][0][c] + red[1][1][c] + red[1][2][c] + red[1][3][c];
    }
}

// ---- conv1: wave-per-node, layers 2/3 as register-weight matvecs, max over k ----
__global__ __launch_bounds__(256) void conv1_kernel(const float* __restrict__ p, const float* __restrict__ q,
        const int* __restrict__ idx,
        const float* __restrict__ sc1v, const float* __restrict__ sh1v,
        const float* __restrict__ w2, const float* __restrict__ b2,
        const float* __restrict__ sc2v, const float* __restrict__ sh2v,
        const float* __restrict__ w3, const float* __restrict__ b3,
        float* __restrict__ x1){
    __shared__ float hA[4][2][64];
    __shared__ float hB[4][2][64];
    int t = threadIdx.x, w = t >> 6, c = t & 63;
    float w2c[64], w3c[64];
#pragma unroll
    for (int f = 0; f < 64; f++){ w2c[f] = w2[f * 64 + c]; w3c[f] = w3[f * 64 + c]; }
    float sc1 = sc1v[c], sh1 = sh1v[c], sc2 = sc2v[c], sh2 = sh2v[c];
    float b2c = b2[c], b3c = b3[c];
    int node = blockIdx.x * 4 + w;
    int b = node >> 11;
    float pc = p[(size_t)node * 64 + c];
    const int* ip = idx + (size_t)node * Kn;
    float acc = -FLT_MAX;
    for (int k = 0; k < Kn; k++){
        int j = ip[k];
        float z = pc + q[((size_t)(b << 11) + j) * 64 + c];
        float h1 = fmaxf(0.f, z * sc1 + sh1);
        hA[w][k & 1][c] = h1;
        const float4* h4 = (const float4*)hA[w][k & 1];
        float z2 = b2c;
#pragma unroll
        for (int f4 = 0; f4 < 16; f4++){
            float4 hv = h4[f4];
            z2 += hv.x * w2c[4*f4] + hv.y * w2c[4*f4+1] + hv.z * w2c[4*f4+2] + hv.w * w2c[4*f4+3];
        }
        float h2 = fmaxf(0.f, z2 * sc2 + sh2);
        hB[w][k & 1][c] = h2;
        const float4* g4 = (const float4*)hB[w][k & 1];
        float z3 = b3c;
#pragma unroll
        for (int f4 = 0; f4 < 16; f4++){
            float4 hv = g4[f4];
            z3 += hv.x * w3c[4*f4] + hv.y * w3c[4*f4+1] + hv.z * w3c[4*f4+2] + hv.w * w3c[4*f4+3];
        }
        acc = fmaxf(acc, z3);
    }
    x1[(size_t)node * 64 + c] = acc;
}

// ---- pre2: u = x1@(W4a-W4b)+b4 (into x2 buffer), v = x1@W4b ----
__global__ __launch_bounds__(256) void pre2_kernel(const float* __restrict__ x1,
        const float* __restrict__ w4, const float* __restrict__ b4,
        float* __restrict__ u, float* __restrict__ v){
    __shared__ float x1s[16][64];
    int t = threadIdx.x;
    int c = t & 127, h = t >> 7;
    float wd[64], wb[64];
#pragma unroll
    for (int f = 0; f < 64; f++){
        float wbv = w4[(64 + f) * 128 + c];
        wb[f] = wbv;
        wd[f] = w4[f * 128 + c] - wbv;
    }
    float b4c = b4[c];
    int base = blockIdx.x * 16;
    for (int i = t; i < 16 * 64; i += 256)
        x1s[i >> 6][i & 63] = x1[(size_t)(base + (i >> 6)) * 64 + (i & 63)];
    __syncthreads();
    for (int n = 0; n < 8; n++){
        int node = base + h * 8 + n;
        const float4* xr = (const float4*)x1s[h * 8 + n];
        float uv = b4c, vv = 0.f;
#pragma unroll
        for (int f4 = 0; f4 < 16; f4++){
            float4 xv = xr[f4];
            uv += xv.x * wd[4*f4] + xv.y * wd[4*f4+1] + xv.z * wd[4*f4+2] + xv.w * wd[4*f4+3];
            vv += xv.x * wb[4*f4] + xv.y * wb[4*f4+1] + xv.z * wb[4*f4+2] + xv.w * wb[4*f4+3];
        }
        u[(size_t)node * 128 + c] = uv;
        v[(size_t)node * 128 + c] = vv;
    }
}

// ---- gmax2: x2[i][c] = u[i][c] + max_k v[j_k][c]  (x2 holds u on entry) ----
__global__ __launch_bounds__(256) void gmax2_kernel(const float* __restrict__ v, const int* __restrict__ idx,
        float* __restrict__ x2){
    int t = threadIdx.x, g = t >> 7, c = t & 127;
    int node = blockIdx.x * 2 + g;
    int b = node >> 11;
    const int* ip = idx + (size_t)node * Kn;
    float vm = -FLT_MAX;
    for (int k = 0; k < Kn; k++){
        int j = ip[k];
        vm = fmaxf(vm, v[((size_t)(b << 11) + j) * 128 + c]);
    }
    x2[(size_t)node * 128 + c] += vm;
}

// ---- out = cat(x1,x2) @ w5 + b5, global max over nodes (encoded atomics) ----
__global__ __launch_bounds__(256) void outpool_kernel(const float* __restrict__ x1, const float* __restrict__ x2,
        const float* __restrict__ w5, const float* __restrict__ b5, unsigned* __restrict__ pooled){
    __shared__ float rows[8][192];
    int t = threadIdx.x;
    int node0 = blockIdx.x * 8;
    for (int i = t; i < 8 * 192; i += 256){
        int e = i / 192, f = i - e * 192;
        int nd = node0 + e;
        rows[e][f] = (f < 64) ? x1[(size_t)nd * 64 + f] : x2[(size_t)nd * 128 + f - 64];
    }
    __syncthreads();
    float z[8];
#pragma unroll
    for (int e = 0; e < 8; e++) z[e] = b5[t];
    for (int f = 0; f < 192; f++){
        float w = w5[f * 256 + t];
#pragma unroll
        for (int e = 0; e < 8; e++) z[e] += rows[e][f] * w;
    }
    float m = z[0];
#pragma unroll
    for (int e = 1; e < 8; e++) m = fmaxf(m, z[e]);
    int b = node0 >> 11;
    atomicMax(&pooled[b * 256 + t], enc_f(m));
}

// ---- head: decode pooled, MLP [256,128,64,4] with training-mode BN over 16 ----
__global__ __launch_bounds__(256) void head_kernel(const unsigned* __restrict__ pooledE,
        const float* __restrict__ w6, const float* __restrict__ b6, const float* __restrict__ g6, const float* __restrict__ bt6,
        const float* __restrict__ w7, const float* __restrict__ b7, const float* __restrict__ g7, const float* __restrict__ bt7,
        const float* __restrict__ w8, const float* __restrict__ b8, float* __restrict__ out){
    __shared__ float P[16][256];
    __shared__ float H6[16][128];
    __shared__ float H7[16][64];
    int t = threadIdx.x;
    for (int i = t; i < 16 * 256; i += 256) P[i >> 8][i & 255] = dec_f(pooledE[i]);
    __syncthreads();
    for (int i = t; i < 16 * 128; i += 256){
        int r = i >> 7, c = i & 127;
        float z = b6[c];
        for (int f = 0; f < 256; f++) z += P[r][f] * w6[f * 128 + c];
        H6[r][c] = z;
    }
    __syncthreads();
    if (t < 128){
        float s = 0.f, q = 0.f;
        for (int r = 0; r < 16; r++){ float v = H6[r][t]; s += v; q += v * v; }
        float mu = s * (1.f / 16.f);
        float var = q * (1.f / 16.f) - mu * mu;
        float sc = g6[t] / sqrtf(var + EPSV);
        float sh = bt6[t] - mu * sc;
        for (int r = 0; r < 16; r++) H6[r][t] = fmaxf(0.f, H6[r][t] * sc + sh);
    }
    __syncthreads();
    for (int i = t; i < 16 * 64; i += 256){
        int r = i >> 6, c = i & 63;
        float z = b7[c];
        for (int f = 0; f < 128; f++) z += H6[r][f] * w7[f * 64 + c];
        H7[r][c] = z;
    }
    __syncthreads();
    if (t < 64){
        float s = 0.f, q = 0.f;
        for (int r = 0; r < 16; r++){ float v = H7[r][t]; s += v; q += v * v; }
        float mu = s * (1.f / 16.f);
        float var = q * (1.f / 16.f) - mu * mu;
        float sc = g7[t] / sqrtf(var + EPSV);
        float sh = bt7[t] - mu * sc;
        for (int r = 0; r < 16; r++) H7[r][t] = fmaxf(0.f, H7[r][t] * sc + sh);
    }
    __syncthreads();
    if (t < 64){
        int r = t >> 2, c = t & 3;
        float z = b8[c];
        for (int f = 0; f < 64; f++) z += H7[r][f] * w8[f * 4 + c];
        out[t] = z;
    }
}

extern "C" void kernel_launch(void* const* d_in, const int* in_sizes, int n_in,
                              void* d_out, int out_size, void* d_ws, size_t ws_size,
                              hipStream_t stream){
    const float* x   = (const float*)d_in[0];
    const float* w1  = (const float*)d_in[1];
    const float* b1  = (const float*)d_in[2];
    const float* g1  = (const float*)d_in[3];
    const float* bt1 = (const float*)d_in[4];
    const float* w2  = (const float*)d_in[5];
    const float* b2  = (const float*)d_in[6];
    const float* g2  = (const float*)d_in[7];
    const float* bt2 = (const float*)d_in[8];
    const float* w3  = (const float*)d_in[9];
    const float* b3  = (const float*)d_in[10];
    const float* w4  = (const float*)d_in[11];
    const float* b4  = (const float*)d_in[12];
    const float* w5  = (const float*)d_in[13];
    const float* b5  = (const float*)d_in[14];
    const float* w6  = (const float*)d_in[15];
    const float* b6  = (const float*)d_in[16];
    const float* g6  = (const float*)d_in[17];
    const float* bt6 = (const float*)d_in[18];
    const float* w7  = (const float*)d_in[19];
    const float* b7  = (const float*)d_in[20];
    const float* g7  = (const float*)d_in[21];
    const float* bt7 = (const float*)d_in[22];
    const float* w8  = (const float*)d_in[23];
    const float* b8  = (const float*)d_in[24];
    float* out = (float*)d_out;

    char* ws = (char*)d_ws;
    size_t off = 0;
    auto alloc = [&](size_t bytes)->char*{
        char* p = ws + off;
        off += (bytes + 255) & ~(size_t)255;
        return p;
    };
    int*      idx1   = (int*)alloc((size_t)EDG * 4);
    int*      idx2   = (int*)alloc((size_t)EDG * 4);
    float*    sq1    = (float*)alloc((size_t)NODES * 4);
    float*    sq2    = (float*)alloc((size_t)NODES * 4);
    float*    x1     = (float*)alloc((size_t)NODES * 64 * 4);
    float*    x2     = (float*)alloc((size_t)NODES * 128 * 4);
    float*    sumP   = (float*)alloc((size_t)NSTATB * 64 * 4);
    float*    ssqP   = (float*)alloc((size_t)NSTATB * 64 * 4);
    float*    scale1 = (float*)alloc(64 * 4);
    float*    shift1 = (float*)alloc(64 * 4);
    float*    scale2 = (float*)alloc(64 * 4);
    float*    shift2 = (float*)alloc(64 * 4);
    unsigned* pooled = (unsigned*)alloc((size_t)Bn * 256 * 4);
    float*    p      = (float*)alloc((size_t)NODES * 64 * 4);
    float*    q      = (float*)alloc((size_t)NODES * 64 * 4);
    float*    v      = p;   // overlay: p,q are dead once conv1 finishes; v = 128 floats/node spans p+q

    hipMemsetAsync(pooled, 0, (size_t)Bn * 256 * 4, stream);

    sq_kernel<8><<<(NODES + 255) / 256, 256, 0, stream>>>(x, sq1);
    knn_kernel<8><<<NODES / 4, 256, 0, stream>>>(x, sq1, idx1);
    pre1_kernel<<<512, 256, 0, stream>>>(x, w1, b1, p, q);
    stats1_kernel<<<NSTATB, 256, 0, stream>>>(p, q, idx1, sumP, ssqP);
    finalize_kernel<<<1, 64, 0, stream>>>(sumP, ssqP, g1, bt1, scale1, shift1, 1.0f / (float)EDG);
    stats2_kernel<<<NSTATB, 256, 0, stream>>>(p, q, idx1, scale1, shift1, w2, b2, sumP, ssqP);
    finalize_kernel<<<1, 64, 0, stream>>>(sumP, ssqP, g2, bt2, scale2, shift2, 1.0f / (float)EDG);
    conv1_kernel<<<NODES / 4, 256, 0, stream>>>(p, q, idx1, scale1, shift1,
                                                w2, b2, scale2, shift2, w3, b3, x1);
    sq_kernel<64><<<(NODES + 255) / 256, 256, 0, stream>>>(x1, sq2);
    knn_kernel<64><<<NODES / 4, 256, 0, stream>>>(x1, sq2, idx2);
    pre2_kernel<<<NODES / 16, 256, 0, stream>>>(x1, w4, b4, x2, v);
    gmax2_kernel<<<NODES / 2, 256, 0, stream>>>(v, idx2, x2);
    outpool_kernel<<<NODES / 8, 256, 0, stream>>>(x1, x2, w5, b5, pooled);
    head_kernel<<<1, 256, 0, stream>>>(pooled, w6, b6, g6, bt6, w7, b7, g7, bt7, w8, b8, out);
}